// Round 11
// baseline (374.201 us; speedup 1.0000x reference)
//
#include <hip/hip_runtime.h>
#include <hip/hip_bf16.h>

// Problem constants (match reference)
constexpr int N_NODES = 50000;
constexpr int N_EDGES = 600000;
constexpr int D       = 128;   // IN_DIM == FEAT
constexpr int N_CLS   = 40;

constexpr float QS = 2048.0f;          // layer-3 gather-table quant scale
constexpr float DQ = 1.0f / 2048.0f;

using bf16x8 = __attribute__((ext_vector_type(8))) short;   // 8 bf16 = 4 VGPR
using f32x4  = __attribute__((ext_vector_type(4))) float;   // MFMA C/D

__device__ inline unsigned short f2bf(float f) {
    __hip_bfloat16 h = __float2bfloat16(f);
    return __builtin_bit_cast(unsigned short, h);
}
__device__ inline float bf2f(unsigned short u) {
    __hip_bfloat16 h = __builtin_bit_cast(__hip_bfloat16, u);
    return __bfloat162float(h);
}
__device__ inline short q16(float v) {
    float s = v * QS;
    s = fminf(fmaxf(s, -32767.f), 32767.f);
    return (short)__float2int_rn(s);
}

// ---------------------------------------------------------------------------
// CSR build: histogram -> block scan -> finalize(+sum-scan) -> scatter
// ---------------------------------------------------------------------------

__global__ void hist_kernel(const int* __restrict__ ei, int* __restrict__ cnt) {
    int e = blockIdx.x * 256 + threadIdx.x;
    if (e < N_EDGES) atomicAdd(&cnt[ei[N_EDGES + e]], 1);
}

__global__ __launch_bounds__(1024) void scan_block_kernel(const int* __restrict__ cnt,
                                                          int* __restrict__ rs,
                                                          int* __restrict__ bsum, int n) {
    __shared__ int t[1024];
    int tid = threadIdx.x;
    int gid = blockIdx.x * 1024 + tid;
    int v = (gid < n) ? cnt[gid] : 0;
    t[tid] = v;
    __syncthreads();
    for (int off = 1; off < 1024; off <<= 1) {
        int u = (tid >= off) ? t[tid - off] : 0;
        __syncthreads();
        t[tid] += u;
        __syncthreads();
    }
    if (gid < n) rs[gid] = t[tid] - v;          // exclusive within block
    if (tid == 1023) bsum[blockIdx.x] = t[1023];
}

__global__ void finalize2_kernel(const int* __restrict__ cnt, int* __restrict__ rs,
                                 int* __restrict__ cursor, float* __restrict__ dinv,
                                 const int* __restrict__ bsum) {
    __shared__ int chunk_off;
    int tid = threadIdx.x;
    int i = blockIdx.x * 256 + tid;
    int chunk = blockIdx.x >> 2;
    if (tid < 64) {
        int v = (tid < chunk) ? bsum[tid] : 0;
#pragma unroll
        for (int o = 1; o < 64; o <<= 1) v += __shfl_xor(v, o);
        if (tid == 0) chunk_off = v;
    }
    __syncthreads();
    if (i < N_NODES) {
        int v = rs[i] + chunk_off;
        rs[i] = v;
        cursor[i] = v;
        dinv[i] = 1.0f / fmaxf((float)cnt[i], 1.0f);
        if (i == 0) rs[N_NODES] = N_EDGES;
    }
}

__global__ void scatter_kernel(const int* __restrict__ ei, int* __restrict__ cursor,
                               int* __restrict__ csr) {
    int e = blockIdx.x * 256 + threadIdx.x;
    if (e < N_EDGES) {
        int d = ei[N_EDGES + e];
        int p = atomicAdd(&cursor[d], 1);
        csr[p] = ei[e];
    }
}

// ---------------------------------------------------------------------------
// Weight split, all 3 layers: w123h/l[layer][n][256] = split [Wl | Wr]
// ---------------------------------------------------------------------------
__global__ void split_w3_kernel(const float* __restrict__ Wl1, const float* __restrict__ Wr1,
                                const float* __restrict__ Wl2, const float* __restrict__ Wr2,
                                const float* __restrict__ Wl3, const float* __restrict__ Wr3,
                                unsigned short* __restrict__ hi, unsigned short* __restrict__ lo) {
    int layer = blockIdx.x >> 7;
    int idx = (blockIdx.x & 127) * 256 + threadIdx.x;
    int n = idx >> 8, k = idx & 255;
    const float* Wl = (layer == 0) ? Wl1 : (layer == 1) ? Wl2 : Wl3;
    const float* Wr = (layer == 0) ? Wr1 : (layer == 1) ? Wr2 : Wr3;
    float v = (k < 128) ? Wl[n * 128 + k] : Wr[n * 128 + (k - 128)];
    unsigned short h = f2bf(v);
    size_t o = (size_t)layer * 32768 + idx;
    hi[o] = h;
    lo[o] = f2bf(v - bf2f(h));
}

__global__ void split_wc_kernel(const float* __restrict__ Wc,
                                unsigned short* __restrict__ hi, unsigned short* __restrict__ lo) {
    int idx = blockIdx.x * 256 + threadIdx.x;
    int n = idx >> 7, k = idx & 127;
    float v = (n < N_CLS) ? Wc[n * 128 + k] : 0.f;
    unsigned short h = f2bf(v);
    hi[idx] = h;
    lo[idx] = f2bf(v - bf2f(h));
}

// ---------------------------------------------------------------------------
// Mean aggregation fp32 (layers 1-2, R6-proven): one wave per node.
// ---------------------------------------------------------------------------
__global__ __launch_bounds__(256) void agg_kernel(const float* __restrict__ feat,
                                                  const int* __restrict__ rs,
                                                  const int* __restrict__ csr,
                                                  const float* __restrict__ dinv,
                                                  float* __restrict__ aggn) {
    int wave = threadIdx.x >> 6;
    int lane = threadIdx.x & 63;
    int node = blockIdx.x * 4 + wave;
    if (node >= N_NODES) return;
    int e0 = rs[node], e1 = rs[node + 1];
    int half = lane >> 5;
    int fl = lane & 31;
    float ax = 0.f, ay = 0.f, az = 0.f, aw = 0.f;

    for (int base = e0; base < e1; base += 64) {
        int cnt = min(64, e1 - base);
        int idxv = (lane < cnt) ? csr[base + lane] : 0;
        int cnt2 = cnt & ~1;
        int j = 0;
        for (; j + 8 <= cnt2; j += 8) {
            int s0 = __shfl(idxv, j + half);
            int s1 = __shfl(idxv, j + 2 + half);
            int s2 = __shfl(idxv, j + 4 + half);
            int s3 = __shfl(idxv, j + 6 + half);
            float4 v0 = *(const float4*)&feat[(size_t)s0 * D + fl * 4];
            float4 v1 = *(const float4*)&feat[(size_t)s1 * D + fl * 4];
            float4 v2 = *(const float4*)&feat[(size_t)s2 * D + fl * 4];
            float4 v3 = *(const float4*)&feat[(size_t)s3 * D + fl * 4];
            ax += v0.x + v1.x + v2.x + v3.x;
            ay += v0.y + v1.y + v2.y + v3.y;
            az += v0.z + v1.z + v2.z + v3.z;
            aw += v0.w + v1.w + v2.w + v3.w;
        }
        for (; j < cnt2; j += 2) {
            int s = __shfl(idxv, j + half);
            float4 v = *(const float4*)&feat[(size_t)s * D + fl * 4];
            ax += v.x; ay += v.y; az += v.z; aw += v.w;
        }
        if (j < cnt) {
            int s = __shfl(idxv, j);
            if (half == 0) {
                float4 v = *(const float4*)&feat[(size_t)s * D + fl * 4];
                ax += v.x; ay += v.y; az += v.z; aw += v.w;
            }
        }
    }
    ax += __shfl(ax, lane ^ 32);
    ay += __shfl(ay, lane ^ 32);
    az += __shfl(az, lane ^ 32);
    aw += __shfl(aw, lane ^ 32);
    if (half == 0) {
        float di = dinv[node];
        float4 o; o.x = ax * di; o.y = ay * di; o.z = az * di; o.w = aw * di;
        *(float4*)&aggn[(size_t)node * D + fl * 4] = o;
    }
}

// ---------------------------------------------------------------------------
// Mean aggregation over int16 table (layer 3 only; R8-proven).
// ---------------------------------------------------------------------------
__global__ __launch_bounds__(256) void agg_q_kernel(const short* __restrict__ feat16,
                                                    const int* __restrict__ rs,
                                                    const int* __restrict__ csr,
                                                    const float* __restrict__ dinv,
                                                    float* __restrict__ aggn) {
    int wave = threadIdx.x >> 6;
    int lane = threadIdx.x & 63;
    int node = blockIdx.x * 4 + wave;
    if (node >= N_NODES) return;
    int e0 = rs[node], e1 = rs[node + 1];
    int q = lane >> 4;
    int fl = lane & 15;
    int acc[8] = {0, 0, 0, 0, 0, 0, 0, 0};

    auto acc8 = [&](uint4 u) {
        acc[0] += (int)(short)(u.x & 0xffff);
        acc[1] += (int)(short)(u.x >> 16);
        acc[2] += (int)(short)(u.y & 0xffff);
        acc[3] += (int)(short)(u.y >> 16);
        acc[4] += (int)(short)(u.z & 0xffff);
        acc[5] += (int)(short)(u.z >> 16);
        acc[6] += (int)(short)(u.w & 0xffff);
        acc[7] += (int)(short)(u.w >> 16);
    };

    for (int base = e0; base < e1; base += 64) {
        int cnt = min(64, e1 - base);
        int idxv = (lane < cnt) ? csr[base + lane] : 0;
        int bulk = cnt & ~15;
        int j = 0;
        for (; j < bulk; j += 16) {
            int s0 = __shfl(idxv, j + q);
            int s1 = __shfl(idxv, j + 4 + q);
            int s2 = __shfl(idxv, j + 8 + q);
            int s3 = __shfl(idxv, j + 12 + q);
            uint4 a = *(const uint4*)&feat16[(size_t)s0 * D + fl * 8];
            uint4 b = *(const uint4*)&feat16[(size_t)s1 * D + fl * 8];
            uint4 c = *(const uint4*)&feat16[(size_t)s2 * D + fl * 8];
            uint4 d = *(const uint4*)&feat16[(size_t)s3 * D + fl * 8];
            acc8(a); acc8(b); acc8(c); acc8(d);
        }
        for (; j < cnt; j += 4) {
            if (j + q < cnt) {
                int s = __shfl(idxv, j + q);
                uint4 a = *(const uint4*)&feat16[(size_t)s * D + fl * 8];
                acc8(a);
            }
        }
    }
#pragma unroll
    for (int i = 0; i < 8; ++i) {
        acc[i] += __shfl(acc[i], lane ^ 16);
        acc[i] += __shfl(acc[i], lane ^ 32);
    }
    if (q == 0) {
        float sc = dinv[node] * DQ;
        float4 o0, o1;
        o0.x = acc[0] * sc; o0.y = acc[1] * sc; o0.z = acc[2] * sc; o0.w = acc[3] * sc;
        o1.x = acc[4] * sc; o1.y = acc[5] * sc; o1.z = acc[6] * sc; o1.w = acc[7] * sc;
        *(float4*)&aggn[(size_t)node * D + fl * 8] = o0;
        *(float4*)&aggn[(size_t)node * D + fl * 8 + 4] = o1;
    }
}

// ---------------------------------------------------------------------------
// gemm_v2: latency-restructured split-bf16 MFMA GEMM (layers 1-2).
//   - W fragments global->register (L2-resident; no W LDS, no W barrier)
//   - A double-buffered in 16KB LDS; ONE raw barrier per kt, fenced BOTH
//     sides (write: lgkmcnt(0)+"memory" before; read: ""::"memory" after)
//   - A+W prefetched one kt ahead; prefetch stays in flight across barrier
// Accumulation order identical to R8's gemm_mfma (BK=32, kt ascending) =>
// bit-identical output.
// ---------------------------------------------------------------------------
__global__ __launch_bounds__(256) void gemm_v2_kernel(const float* __restrict__ Aagg,
                                                      const float* __restrict__ Ax,
                                                      const unsigned short* __restrict__ Whi,
                                                      const unsigned short* __restrict__ Wlo,
                                                      const float* __restrict__ bias,
                                                      short* __restrict__ out16,
                                                      float* __restrict__ outp, int M) {
    __shared__ __align__(16) unsigned short AhS[2][64 * 32];   // 2 x 4KB
    __shared__ __align__(16) unsigned short AlS[2][64 * 32];   // 2 x 4KB

    int tid = threadIdx.x;
    int lane = tid & 63;
    int wid = tid >> 6;
    int wr = wid >> 1;
    int wc = wid & 1;
    int lr = lane & 15;
    int kg = (lane >> 4) * 8;
    int row0 = blockIdx.x * 64;

    // A staging slot: 64 rows x 32 k, 1 slot (8 floats) per thread
    int arow = tid >> 2;
    int ak8 = (tid & 3) * 8;
    int agr = row0 + arow;
    if (agr >= M) agr = M - 1;
    const float* aag = &Aagg[(size_t)agr * D + ak8];
    const float* axp = &Ax[(size_t)agr * D + ak8];
    int aboff = (arow << 6) + (ak8 << 1);
    aboff ^= (arow & 7) << 4;

    // W fragment pointers (this lane's B operands)
    const unsigned short* whp[4];
    const unsigned short* wlp[4];
#pragma unroll
    for (int j = 0; j < 4; ++j) {
        int n = wc * 64 + j * 16 + lr;
        whp[j] = &Whi[n * 256 + kg];
        wlp[j] = &Wlo[n * 256 + kg];
    }

    f32x4 acc[2][4];
#pragma unroll
    for (int f = 0; f < 2; ++f)
#pragma unroll
        for (int j = 0; j < 4; ++j) acc[f][j] = (f32x4){0.f, 0.f, 0.f, 0.f};

    // prologue: kt=0 data
    float4 a0c = *(const float4*)(aag);
    float4 a1c = *(const float4*)(aag + 4);
    bf16x8 whc[4], wlc[4];
#pragma unroll
    for (int j = 0; j < 4; ++j) {
        whc[j] = *(const bf16x8*)(whp[j]);
        wlc[j] = *(const bf16x8*)(wlp[j]);
    }

#pragma unroll
    for (int kt = 0; kt < 8; ++kt) {
        unsigned short* AhB = AhS[kt & 1];
        unsigned short* AlB = AlS[kt & 1];

        // split current A into LDS buf
        {
            float fv[8] = {a0c.x, a0c.y, a0c.z, a0c.w, a1c.x, a1c.y, a1c.z, a1c.w};
            union { unsigned short u[8]; uint4 q; } ph, pl;
#pragma unroll
            for (int j = 0; j < 8; ++j) {
                unsigned short h = f2bf(fv[j]);
                ph.u[j] = h;
                pl.u[j] = f2bf(fv[j] - bf2f(h));
            }
            *(uint4*)((char*)AhB + aboff) = ph.q;
            *(uint4*)((char*)AlB + aboff) = pl.q;
        }

        // prefetch kt+1 (issued BEFORE the barrier; stays in flight across it)
        float4 a0n, a1n;
        bf16x8 whn[4], wln[4];
        if (kt < 7) {
            int ktn = kt + 1;
            const float* src = (ktn < 4) ? aag : axp;
            int kcol = (ktn & 3) * 32;
            a0n = *(const float4*)(src + kcol);
            a1n = *(const float4*)(src + kcol + 4);
            int wof = ktn * 32;
#pragma unroll
            for (int j = 0; j < 4; ++j) {
                whn[j] = *(const bf16x8*)(whp[j] + wof);
                wln[j] = *(const bf16x8*)(wlp[j] + wof);
            }
        }

        // raw barrier, fenced both sides:
        //   write side: drain this wave's LDS writes, compiler may not sink them
        //   read side: compiler may not hoist the ds_reads above the barrier
        asm volatile("s_waitcnt lgkmcnt(0)" ::: "memory");
        __builtin_amdgcn_s_barrier();
        asm volatile("" ::: "memory");

        // MFMA(kt): A frags from LDS, B frags from registers
        {
            bf16x8 ah[2], al[2];
#pragma unroll
            for (int f = 0; f < 2; ++f) {
                int row = wr * 32 + f * 16 + lr;
                int boff = (row << 6) + (kg << 1);
                boff ^= (row & 7) << 4;
                ah[f] = *(const bf16x8*)((char*)AhB + boff);
                al[f] = *(const bf16x8*)((char*)AlB + boff);
            }
#pragma unroll
            for (int f = 0; f < 2; ++f)
#pragma unroll
                for (int j = 0; j < 4; ++j) {
                    acc[f][j] = __builtin_amdgcn_mfma_f32_16x16x32_bf16(ah[f], whc[j], acc[f][j], 0, 0, 0);
                    acc[f][j] = __builtin_amdgcn_mfma_f32_16x16x32_bf16(ah[f], wlc[j], acc[f][j], 0, 0, 0);
                    acc[f][j] = __builtin_amdgcn_mfma_f32_16x16x32_bf16(al[f], whc[j], acc[f][j], 0, 0, 0);
                }
        }

        // rotate prefetched data in
        if (kt < 7) {
            a0c = a0n; a1c = a1n;
#pragma unroll
            for (int j = 0; j < 4; ++j) { whc[j] = whn[j]; wlc[j] = wln[j]; }
        }
    }

    // epilogue: bias + relu (+ optional int16 twin). D map: row=(l>>4)*4+r, col=l&15
#pragma unroll
    for (int f = 0; f < 2; ++f)
#pragma unroll
        for (int j = 0; j < 4; ++j) {
            int c = wc * 64 + j * 16 + lr;
            float b = bias[c];
#pragma unroll
            for (int r = 0; r < 4; ++r) {
                int gr = row0 + wr * 32 + f * 16 + (lane >> 4) * 4 + r;
                if (gr < M) {
                    float v = fmaxf(acc[f][j][r] + b, 0.f);
                    outp[(size_t)gr * D + c] = v;
                    if (out16) out16[(size_t)gr * D + c] = q16(v);
                }
            }
        }
}

// ---------------------------------------------------------------------------
// Layer-3 GEMM + residual + fused classifier (UNCHANGED from R8 = control).
// ---------------------------------------------------------------------------
__global__ __launch_bounds__(256) void gemm_cls_kernel(const float* __restrict__ Aagg,
                                                       const float* __restrict__ Ax,
                                                       const unsigned short* __restrict__ Whi,
                                                       const unsigned short* __restrict__ Wlo,
                                                       const float* __restrict__ bias,
                                                       const float* __restrict__ residf,
                                                       const unsigned short* __restrict__ Wch,
                                                       const unsigned short* __restrict__ Wcl,
                                                       const float* __restrict__ bc,
                                                       float* __restrict__ outp, int M) {
    __shared__ __align__(16) char smem[49152];
    char* AhB = smem;
    char* AlB = smem + 8192;
    char* WhB = smem + 16384;
    char* WlB = smem + 32768;

    int tid = threadIdx.x;
    int lane = tid & 63;
    int wid = tid >> 6;
    int wr = wid >> 1;
    int wc = wid & 1;
    int lr = lane & 15;
    int kg = (lane >> 4) * 8;
    int row0 = blockIdx.x * 64;

    f32x4 acc[2][4];
#pragma unroll
    for (int f = 0; f < 2; ++f)
#pragma unroll
        for (int j = 0; j < 4; ++j) acc[f][j] = (f32x4){0.f, 0.f, 0.f, 0.f};

    for (int kt = 0; kt < 4; ++kt) {
        const float* Asrc = (kt < 2) ? Aagg : Ax;
        int kcol = (kt & 1) * 64;
#pragma unroll
        for (int it = 0; it < 2; ++it) {
            int slot = tid + it * 256;
            int row = slot >> 3;
            int k8 = (slot & 7) * 8;
            int gr = row0 + row;
            if (gr >= M) gr = M - 1;
            const float* p = &Asrc[(size_t)gr * D + kcol + k8];
            float4 v0 = *(const float4*)p;
            float4 v1 = *(const float4*)(p + 4);
            float fv[8] = {v0.x, v0.y, v0.z, v0.w, v1.x, v1.y, v1.z, v1.w};
            union { unsigned short u[8]; uint4 q; } ph, pl;
#pragma unroll
            for (int j = 0; j < 8; ++j) {
                unsigned short h = f2bf(fv[j]);
                ph.u[j] = h;
                pl.u[j] = f2bf(fv[j] - bf2f(h));
            }
            int boff = (row << 7) + (k8 << 1);
            boff ^= (row & 7) << 4;
            *(uint4*)(AhB + boff) = ph.q;
            *(uint4*)(AlB + boff) = pl.q;
        }
#pragma unroll
        for (int it = 0; it < 4; ++it) {
            int slot = tid + it * 256;
            int n = slot >> 3;
            int k8 = (slot & 7) * 8;
            size_t gsrc = (size_t)n * 256 + kt * 64 + k8;
            uint4 h = *(const uint4*)&Whi[gsrc];
            uint4 l = *(const uint4*)&Wlo[gsrc];
            int boff = (n << 7) + (k8 << 1);
            boff ^= (n & 7) << 4;
            *(uint4*)(WhB + boff) = h;
            *(uint4*)(WlB + boff) = l;
        }
        __syncthreads();
#pragma unroll
        for (int ks = 0; ks < 2; ++ks) {
            int kk = ks * 32 + kg;
            bf16x8 ah[2], al[2];
#pragma unroll
            for (int f = 0; f < 2; ++f) {
                int row = wr * 32 + f * 16 + lr;
                int boff = (row << 7) + (kk << 1);
                boff ^= (row & 7) << 4;
                ah[f] = *(const bf16x8*)(AhB + boff);
                al[f] = *(const bf16x8*)(AlB + boff);
            }
            bf16x8 bh[4], bl[4];
#pragma unroll
            for (int j = 0; j < 4; ++j) {
                int n = wc * 64 + j * 16 + lr;
                int boff = (n << 7) + (kk << 1);
                boff ^= (n & 7) << 4;
                bh[j] = *(const bf16x8*)(WhB + boff);
                bl[j] = *(const bf16x8*)(WlB + boff);
            }
#pragma unroll
            for (int f = 0; f < 2; ++f)
#pragma unroll
                for (int j = 0; j < 4; ++j) {
                    acc[f][j] = __builtin_amdgcn_mfma_f32_16x16x32_bf16(ah[f], bh[j], acc[f][j], 0, 0, 0);
                    acc[f][j] = __builtin_amdgcn_mfma_f32_16x16x32_bf16(ah[f], bl[j], acc[f][j], 0, 0, 0);
                    acc[f][j] = __builtin_amdgcn_mfma_f32_16x16x32_bf16(al[f], bh[j], acc[f][j], 0, 0, 0);
                }
        }
        __syncthreads();
    }

    f32x4 acc2[3];
#pragma unroll
    for (int j = 0; j < 3; ++j) acc2[j] = (f32x4){0.f, 0.f, 0.f, 0.f};

    for (int p = 0; p < 2; ++p) {
#pragma unroll
        for (int it = 0; it < 2; ++it) {
            int slot = tid + it * 256;
            if (slot < 384) {
                int n = slot >> 3;
                int k8 = (slot & 7) * 8;
                size_t gsrc = (size_t)n * 128 + p * 64 + k8;
                uint4 h = *(const uint4*)&Wch[gsrc];
                uint4 l = *(const uint4*)&Wcl[gsrc];
                int boff = (n << 7) + (k8 << 1);
                boff ^= (n & 7) << 4;
                *(uint4*)(WhB + boff) = h;
                *(uint4*)(WlB + boff) = l;
            }
        }
        if (wc == p) {
#pragma unroll
            for (int f = 0; f < 2; ++f)
#pragma unroll
                for (int j = 0; j < 4; ++j) {
                    int c = wc * 64 + j * 16 + lr;
                    float b = bias[c];
#pragma unroll
                    for (int r = 0; r < 4; ++r) {
                        int row = wr * 32 + f * 16 + (lane >> 4) * 4 + r;
                        int gr = row0 + row;
                        int gra = (gr < M) ? gr : (M - 1);
                        float v = fmaxf(acc[f][j][r] + b, 0.f);
                        v += residf[(size_t)gra * D + c];
                        int kloc = j * 16 + lr;
                        int boff = (row << 7) + (kloc << 1);
                        boff ^= (row & 7) << 4;
                        unsigned short h = f2bf(v);
                        *(unsigned short*)(AhB + boff) = h;
                        *(unsigned short*)(AlB + boff) = f2bf(v - bf2f(h));
                    }
                }
        }
        __syncthreads();

#pragma unroll
        for (int ks = 0; ks < 2; ++ks) {
            int kk = ks * 32 + kg;
            int row = wid * 16 + lr;
            int boffA = (row << 7) + (kk << 1);
            boffA ^= (row & 7) << 4;
            bf16x8 ah = *(const bf16x8*)(AhB + boffA);
            bf16x8 al = *(const bf16x8*)(AlB + boffA);
#pragma unroll
            for (int j = 0; j < 3; ++j) {
                int n = j * 16 + lr;
                int boffB = (n << 7) + (kk << 1);
                boffB ^= (n & 7) << 4;
                bf16x8 bh = *(const bf16x8*)(WhB + boffB);
                bf16x8 bl = *(const bf16x8*)(WlB + boffB);
                acc2[j] = __builtin_amdgcn_mfma_f32_16x16x32_bf16(ah, bh, acc2[j], 0, 0, 0);
                acc2[j] = __builtin_amdgcn_mfma_f32_16x16x32_bf16(ah, bl, acc2[j], 0, 0, 0);
                acc2[j] = __builtin_amdgcn_mfma_f32_16x16x32_bf16(al, bh, acc2[j], 0, 0, 0);
            }
        }
        __syncthreads();
    }

#pragma unroll
    for (int j = 0; j < 3; ++j) {
        int c = j * 16 + lr;
        if (c < N_CLS) {
            float b = bc[c];
#pragma unroll
            for (int r = 0; r < 4; ++r) {
                int gr = row0 + wid * 16 + (lane >> 4) * 4 + r;
                if (gr < M) outp[(size_t)gr * N_CLS + c] = acc2[j][r] + b;
            }
        }
    }
}

// ---------------------------------------------------------------------------
extern "C" void kernel_launch(void* const* d_in, const int* in_sizes, int n_in,
                              void* d_out, int out_size, void* d_ws, size_t ws_size,
                              hipStream_t stream) {
    const float* x   = (const float*)d_in[0];
    const int*   ei  = (const int*)d_in[1];
    const float* Wl1 = (const float*)d_in[2];
    const float* bl1 = (const float*)d_in[3];
    const float* Wr1 = (const float*)d_in[4];
    const float* Wl2 = (const float*)d_in[5];
    const float* bl2 = (const float*)d_in[6];
    const float* Wr2 = (const float*)d_in[7];
    const float* Wl3 = (const float*)d_in[8];
    const float* bl3 = (const float*)d_in[9];
    const float* Wr3 = (const float*)d_in[10];
    const float* Wc  = (const float*)d_in[11];
    const float* bc  = (const float*)d_in[12];
    float* out = (float*)d_out;

    char* w = (char*)d_ws;
    size_t off = 0;
    auto carve = [&](size_t bytes) -> void* {
        void* p = w + off;
        off = (off + bytes + 255) & ~(size_t)255;
        return p;
    };
    int*   cnt    = (int*)carve((size_t)N_NODES * 4);
    int*   rs     = (int*)carve((size_t)(N_NODES + 1) * 4);
    int*   cursor = (int*)carve((size_t)N_NODES * 4);
    float* dinv   = (float*)carve((size_t)N_NODES * 4);
    int*   bsum   = (int*)carve(64 * 4);
    int*   csr    = (int*)carve((size_t)N_EDGES * 4);
    float* aggn   = (float*)carve((size_t)N_NODES * D * 4);   // 25.6 MB
    float* bufA   = (float*)carve((size_t)N_NODES * D * 4);   // 25.6 MB
    float* bufB   = (float*)carve((size_t)N_NODES * D * 4);   // 25.6 MB
    short* t16    = (short*)carve((size_t)N_NODES * D * 2);   // 12.8 MB L3 gather twin
    unsigned short* w123h = (unsigned short*)carve(3 * 128 * 256 * 2);
    unsigned short* w123l = (unsigned short*)carve(3 * 128 * 256 * 2);
    unsigned short* wch   = (unsigned short*)carve(48 * 128 * 2);
    unsigned short* wcl   = (unsigned short*)carve(48 * 128 * 2);
    (void)ws_size;

    const int NBLK_SCAN = (N_NODES + 1023) / 1024;           // 49
    const int GRID_E = (N_EDGES + 255) / 256;                // 2344
    const int GRID_N = (N_NODES + 255) / 256;                // 196
    const int GRID_AGG = (N_NODES + 3) / 4;                  // 12500
    const int GRID_GEMM = (N_NODES + 63) / 64;               // 782

    // CSR build + weight splits
    hipMemsetAsync(cnt, 0, (size_t)N_NODES * 4, stream);
    hipLaunchKernelGGL(hist_kernel, dim3(GRID_E), dim3(256), 0, stream, ei, cnt);
    hipLaunchKernelGGL(split_w3_kernel, dim3(384), dim3(256), 0, stream,
                       Wl1, Wr1, Wl2, Wr2, Wl3, Wr3, w123h, w123l);
    hipLaunchKernelGGL(split_wc_kernel, dim3(24), dim3(256), 0, stream, Wc, wch, wcl);
    hipLaunchKernelGGL(scan_block_kernel, dim3(NBLK_SCAN), dim3(1024), 0, stream, cnt, rs, bsum, N_NODES);
    hipLaunchKernelGGL(finalize2_kernel, dim3(GRID_N), dim3(256), 0, stream, cnt, rs, cursor, dinv, bsum);
    hipLaunchKernelGGL(scatter_kernel, dim3(GRID_E), dim3(256), 0, stream, ei, cursor, csr);

    // Layer 1: agg fp32 -> gemm_v2 -> bufA
    hipLaunchKernelGGL(agg_kernel, dim3(GRID_AGG), dim3(256), 0, stream, x, rs, csr, dinv, aggn);
    hipLaunchKernelGGL(gemm_v2_kernel, dim3(GRID_GEMM), dim3(256), 0, stream,
                       aggn, x, w123h, w123l, bl1, (short*)nullptr, bufA, N_NODES);
    // Layer 2: agg fp32 -> gemm_v2 -> bufB + t16 twin (for L3 gather)
    hipLaunchKernelGGL(agg_kernel, dim3(GRID_AGG), dim3(256), 0, stream, bufA, rs, csr, dinv, aggn);
    hipLaunchKernelGGL(gemm_v2_kernel, dim3(GRID_GEMM), dim3(256), 0, stream,
                       aggn, bufA, w123h + 32768, w123l + 32768, bl2, t16, bufB, N_NODES);
    // Layer 3: agg int16 -> GEMM + resid + classifier (control kernel)
    hipLaunchKernelGGL(agg_q_kernel, dim3(GRID_AGG), dim3(256), 0, stream, t16, rs, csr, dinv, aggn);
    hipLaunchKernelGGL(gemm_cls_kernel, dim3(GRID_GEMM), dim3(256), 0, stream,
                       aggn, bufB, w123h + 65536, w123l + 65536, bl3, bufB,
                       wch, wcl, bc, out, N_NODES);
}